// Round 1
// baseline (537.674 us; speedup 1.0000x reference)
//
#include <hip/hip_runtime.h>

#define BB 4096      // batch rows
#define DD 1024      // feature dim

typedef float f32x4 __attribute__((ext_vector_type(4)));
typedef short bf16x8 __attribute__((ext_vector_type(8)));

__device__ __forceinline__ unsigned short f2bf(float f) {
  unsigned u = __float_as_uint(f);
  unsigned r = u + 0x7fffu + ((u >> 16) & 1u);
  return (unsigned short)(r >> 16);
}

__device__ __forceinline__ void async16(const void* g, void* l) {
  __builtin_amdgcn_global_load_lds(
      (const __attribute__((address_space(1))) void*)g,
      (__attribute__((address_space(3))) void*)l,
      16, 0, 0);
}

// ---------------- Phase 1: normalize anchor rows -> bf16 ----------------
__global__ __launch_bounds__(256) void norm_anchor(const float* __restrict__ x,
                                                   unsigned short* __restrict__ y) {
  __shared__ float sred[4];
  const int row = blockIdx.x;
  const int tid = threadIdx.x;
  const float4 v = ((const float4*)(x + (size_t)row * DD))[tid];
  float ss = v.x * v.x + v.y * v.y + v.z * v.z + v.w * v.w;
#pragma unroll
  for (int off = 32; off > 0; off >>= 1) ss += __shfl_xor(ss, off, 64);
  if ((tid & 63) == 0) sred[tid >> 6] = ss;
  __syncthreads();
  const float tot = sred[0] + sred[1] + sred[2] + sred[3];
  const float inv = 1.0f / fmaxf(sqrtf(tot), 1e-12f);
  ushort4 o;
  o.x = f2bf(v.x * inv);
  o.y = f2bf(v.y * inv);
  o.z = f2bf(v.z * inv);
  o.w = f2bf(v.w * inv);
  ((ushort4*)(y + (size_t)row * DD))[tid] = o;
}

// ------- Phase 2: gather centroid row per (j, scale), normalize -> bf16; 1/temp -------
__global__ __launch_bounds__(256) void gather_norm(
    const int* __restrict__ index,
    const int* __restrict__ i2c0, const int* __restrict__ i2c1, const int* __restrict__ i2c2,
    const float* __restrict__ c0, const float* __restrict__ c1, const float* __restrict__ c2,
    const float* __restrict__ d0, const float* __restrict__ d1, const float* __restrict__ d2,
    unsigned short* __restrict__ p16, float* __restrict__ rt) {
  __shared__ float sred[4];
  const int j = blockIdx.x;
  const int s = blockIdx.y;
  const int tid = threadIdx.x;
  const int* i2c = (s == 0) ? i2c0 : (s == 1) ? i2c1 : i2c2;
  const float* cent = (s == 0) ? c0 : (s == 1) ? c1 : c2;
  const float* dens = (s == 0) ? d0 : (s == 1) ? d1 : d2;
  const int pid = i2c[index[j]];
  const float4 v = ((const float4*)(cent + (size_t)pid * DD))[tid];
  float ss = v.x * v.x + v.y * v.y + v.z * v.z + v.w * v.w;
#pragma unroll
  for (int off = 32; off > 0; off >>= 1) ss += __shfl_xor(ss, off, 64);
  if ((tid & 63) == 0) sred[tid >> 6] = ss;
  __syncthreads();
  const float tot = sred[0] + sred[1] + sred[2] + sred[3];
  const float inv = 1.0f / fmaxf(sqrtf(tot), 1e-12f);
  unsigned short* out = p16 + ((size_t)s * BB + j) * DD;
  ushort4 o;
  o.x = f2bf(v.x * inv);
  o.y = f2bf(v.y * inv);
  o.z = f2bf(v.z * inv);
  o.w = f2bf(v.w * inv);
  ((ushort4*)out)[tid] = o;
  if (tid == 0) rt[s * BB + j] = 1.0f / dens[pid];
}

// ---------------- Phase 3: sim = A (bf16 [4096x1024]) @ B^T (bf16 [4096x1024]) ----------------
// 128x128 tile per block, 256 threads = 4 waves (2x2), each wave 64x64 via 4x4 MFMA 16x16x32.
__global__ __launch_bounds__(256) void gemm_nt_bf16(const unsigned short* __restrict__ A,
                                                    const unsigned short* __restrict__ Bm,
                                                    float* __restrict__ C) {
  __shared__ __align__(16) unsigned short lA[128 * 32];
  __shared__ __align__(16) unsigned short lB[128 * 32];
  const int tid = threadIdx.x;
  const int lane = tid & 63;
  const int wave = tid >> 6;
  const int m0 = blockIdx.y * 128;
  const int n0 = blockIdx.x * 128;

  f32x4 acc[4][4];
#pragma unroll
  for (int mi = 0; mi < 4; ++mi)
#pragma unroll
    for (int ni = 0; ni < 4; ++ni) acc[mi][ni] = (f32x4){0.f, 0.f, 0.f, 0.f};

  // staging geometry: each lane moves 16B (8 bf16); 64B per row; one wave-call = 16 rows
  const int srow = lane >> 2;        // 0..15 within chunk
  const int scol = (lane & 3) * 8;   // bf16 element offset within row

  // fragment geometry
  const int wm = (wave >> 1) * 64;
  const int wn = (wave & 1) * 64;
  const int fr = lane & 15;
  const int fk = (lane >> 4) * 8;

  for (int k0 = 0; k0 < DD; k0 += 32) {
#pragma unroll
    for (int c = 0; c < 2; ++c) {
      const int chunk = wave * 2 + c;            // 0..7, wave-uniform
      const int r = chunk * 16 + srow;           // 0..127
      const unsigned short* ga = A + (size_t)(m0 + r) * DD + k0 + scol;
      const unsigned short* gb = Bm + (size_t)(n0 + r) * DD + k0 + scol;
      async16(ga, &lA[chunk * 512]);
      async16(gb, &lB[chunk * 512]);
    }
    __syncthreads();  // drains vmcnt(0) then barrier: staged data visible

    bf16x8 af[4], bf[4];
#pragma unroll
    for (int mi = 0; mi < 4; ++mi)
      af[mi] = *(const bf16x8*)&lA[(wm + mi * 16 + fr) * 32 + fk];
#pragma unroll
    for (int ni = 0; ni < 4; ++ni)
      bf[ni] = *(const bf16x8*)&lB[(wn + ni * 16 + fr) * 32 + fk];
#pragma unroll
    for (int mi = 0; mi < 4; ++mi)
#pragma unroll
      for (int ni = 0; ni < 4; ++ni)
        acc[mi][ni] = __builtin_amdgcn_mfma_f32_16x16x32_bf16(af[mi], bf[ni], acc[mi][ni], 0, 0, 0);
    __syncthreads();  // all waves done reading LDS before next stage overwrites
  }

  // epilogue: D[row=(lane>>4)*4+r][col=lane&15] per 16x16 tile
  const int cm = (lane >> 4) * 4;
#pragma unroll
  for (int mi = 0; mi < 4; ++mi)
#pragma unroll
    for (int ni = 0; ni < 4; ++ni) {
      const int col = n0 + wn + ni * 16 + fr;
#pragma unroll
      for (int r = 0; r < 4; ++r) {
        const int rowi = m0 + wm + mi * 16 + cm + r;
        C[(size_t)rowi * BB + col] = acc[mi][ni][r];
      }
    }
}

// ---------------- Phase 4: per-row CE with faithful temperature mapping ----------------
// logits col mapping for row i: c==i -> rt[0]; c<i -> rt[c+1]; c>i -> rt[c]
__global__ __launch_bounds__(256) void ce_kernel(const float* __restrict__ sim,
                                                 const float* __restrict__ rt,
                                                 float* __restrict__ ce) {
  __shared__ float slog[BB];
  __shared__ float sred[8];
  const int i = blockIdx.x;
  const int tid = threadIdx.x;
  const int lane = tid & 63;
  const int wave = tid >> 6;
  const float* row = sim + (size_t)i * BB;
  const float r0 = rt[0];
  float lmax = -3.4e38f;
  for (int c = tid; c < BB; c += 256) {
    const float v = row[c];
    const float rr = (c == i) ? r0 : ((c < i) ? rt[c + 1] : rt[c]);
    const float l = v * rr;
    slog[c] = l;
    lmax = fmaxf(lmax, l);
  }
#pragma unroll
  for (int off = 32; off > 0; off >>= 1) lmax = fmaxf(lmax, __shfl_xor(lmax, off, 64));
  if (lane == 0) sred[wave] = lmax;
  __syncthreads();
  const float m = fmaxf(fmaxf(sred[0], sred[1]), fmaxf(sred[2], sred[3]));
  float sum = 0.f;
  for (int c = tid; c < BB; c += 256) sum += __expf(slog[c] - m);
#pragma unroll
  for (int off = 32; off > 0; off >>= 1) sum += __shfl_xor(sum, off, 64);
  if (lane == 0) sred[4 + wave] = sum;
  __syncthreads();
  if (tid == 0) {
    const float tot = sred[4] + sred[5] + sred[6] + sred[7];
    ce[i] = m + logf(tot) - slog[i];  // lse - logits[:,0]
  }
}

// ---------------- Phase 5: loss = ce0/27 + ce1/9 + ce2/3 ----------------
__global__ __launch_bounds__(256) void combine(const float* __restrict__ ce,
                                               float* __restrict__ out) {
  const int i = blockIdx.x * 256 + threadIdx.x;
  out[i] = ce[i] * (1.0f / 27.0f) + ce[BB + i] * (1.0f / 9.0f) + ce[2 * BB + i] * (1.0f / 3.0f);
}

extern "C" void kernel_launch(void* const* d_in, const int* in_sizes, int n_in,
                              void* d_out, int out_size, void* d_ws, size_t ws_size,
                              hipStream_t stream) {
  const float* anchor = (const float*)d_in[0];
  const int* index    = (const int*)d_in[1];
  const int* i2c0     = (const int*)d_in[2];
  const float* c0     = (const float*)d_in[3];
  const float* de0    = (const float*)d_in[4];
  const int* i2c1     = (const int*)d_in[5];
  const float* c1     = (const float*)d_in[6];
  const float* de1    = (const float*)d_in[7];
  const int* i2c2     = (const int*)d_in[8];
  const float* c2     = (const float*)d_in[9];
  const float* de2    = (const float*)d_in[10];

  char* ws = (char*)d_ws;
  const size_t A16_OFF = 0;                       // 4096*1024*2   = 8 MB
  const size_t P16_OFF = A16_OFF + (size_t)BB * DD * 2;           // 24 MB (3 scales)
  const size_t RT_OFF  = P16_OFF + (size_t)3 * BB * DD * 2;       // 48 KB
  const size_t CE_OFF  = RT_OFF + (size_t)3 * BB * 4;             // 48 KB
  const size_t SIM_OFF = CE_OFF + (size_t)3 * BB * 4;             // 64 MB (reused per scale)

  unsigned short* a16 = (unsigned short*)(ws + A16_OFF);
  unsigned short* p16 = (unsigned short*)(ws + P16_OFF);
  float* rt  = (float*)(ws + RT_OFF);
  float* cebuf = (float*)(ws + CE_OFF);
  float* sim = (float*)(ws + SIM_OFF);
  float* out = (float*)d_out;

  norm_anchor<<<BB, 256, 0, stream>>>(anchor, a16);
  gather_norm<<<dim3(BB, 3), 256, 0, stream>>>(index, i2c0, i2c1, i2c2,
                                               c0, c1, c2, de0, de1, de2, p16, rt);
  for (int s = 0; s < 3; ++s) {
    gemm_nt_bf16<<<dim3(BB / 128, BB / 128), 256, 0, stream>>>(
        a16, p16 + (size_t)s * BB * DD, sim);
    ce_kernel<<<BB, 256, 0, stream>>>(sim, rt + (size_t)s * BB, cebuf + (size_t)s * BB);
  }
  combine<<<BB / 256, 256, 0, stream>>>(cebuf, out);
}

// Round 2
// 441.304 us; speedup vs baseline: 1.2184x; 1.2184x over previous
//
#include <hip/hip_runtime.h>

#define BB 4096      // batch rows
#define DD 1024      // feature dim
#define RTS (BB + 16) // padded per-scale stride for rt (avoid OOB eager load)

typedef float f32x4 __attribute__((ext_vector_type(4)));
typedef short bf16x8 __attribute__((ext_vector_type(8)));

__device__ __forceinline__ unsigned short f2bf(float f) {
  unsigned u = __float_as_uint(f);
  unsigned r = u + 0x7fffu + ((u >> 16) & 1u);
  return (unsigned short)(r >> 16);
}

__device__ __forceinline__ void async16(const void* g, void* l) {
  __builtin_amdgcn_global_load_lds(
      (const __attribute__((address_space(1))) void*)g,
      (__attribute__((address_space(3))) void*)l,
      16, 0, 0);
}

// ---------------- Phase 1: normalize anchor rows -> bf16 ----------------
__global__ __launch_bounds__(256) void norm_anchor(const float* __restrict__ x,
                                                   unsigned short* __restrict__ y) {
  __shared__ float sred[4];
  const int row = blockIdx.x;
  const int tid = threadIdx.x;
  const float4 v = ((const float4*)(x + (size_t)row * DD))[tid];
  float ss = v.x * v.x + v.y * v.y + v.z * v.z + v.w * v.w;
#pragma unroll
  for (int off = 32; off > 0; off >>= 1) ss += __shfl_xor(ss, off, 64);
  if ((tid & 63) == 0) sred[tid >> 6] = ss;
  __syncthreads();
  const float tot = sred[0] + sred[1] + sred[2] + sred[3];
  const float inv = 1.0f / fmaxf(sqrtf(tot), 1e-12f);
  ushort4 o;
  o.x = f2bf(v.x * inv);
  o.y = f2bf(v.y * inv);
  o.z = f2bf(v.z * inv);
  o.w = f2bf(v.w * inv);
  ((ushort4*)(y + (size_t)row * DD))[tid] = o;
}

// ------- Phase 2: gather centroid row per (j, scale), normalize -> bf16; 1/temp; zero acc -------
__global__ __launch_bounds__(256) void gather_norm(
    const int* __restrict__ index,
    const int* __restrict__ i2c0, const int* __restrict__ i2c1, const int* __restrict__ i2c2,
    const float* __restrict__ c0, const float* __restrict__ c1, const float* __restrict__ c2,
    const float* __restrict__ d0, const float* __restrict__ d1, const float* __restrict__ d2,
    unsigned short* __restrict__ p16, float* __restrict__ rt,
    float* __restrict__ rowacc) {
  __shared__ float sred[4];
  const int j = blockIdx.x;
  const int s = blockIdx.y;
  const int tid = threadIdx.x;
  const int* i2c = (s == 0) ? i2c0 : (s == 1) ? i2c1 : i2c2;
  const float* cent = (s == 0) ? c0 : (s == 1) ? c1 : c2;
  const float* dens = (s == 0) ? d0 : (s == 1) ? d1 : d2;
  const int pid = i2c[index[j]];
  const float4 v = ((const float4*)(cent + (size_t)pid * DD))[tid];
  float ss = v.x * v.x + v.y * v.y + v.z * v.z + v.w * v.w;
#pragma unroll
  for (int off = 32; off > 0; off >>= 1) ss += __shfl_xor(ss, off, 64);
  if ((tid & 63) == 0) sred[tid >> 6] = ss;
  __syncthreads();
  const float tot = sred[0] + sred[1] + sred[2] + sred[3];
  const float inv = 1.0f / fmaxf(sqrtf(tot), 1e-12f);
  unsigned short* out = p16 + ((size_t)s * BB + j) * DD;
  ushort4 o;
  o.x = f2bf(v.x * inv);
  o.y = f2bf(v.y * inv);
  o.z = f2bf(v.z * inv);
  o.w = f2bf(v.w * inv);
  ((ushort4*)out)[tid] = o;
  if (tid == 0) rt[(size_t)s * RTS + j] = 1.0f / dens[pid];
  if (tid == 1) rowacc[(size_t)s * BB + j] = 0.0f;  // zero sum-exp accumulator
}

// -------- Phase 3: fused sim-GEMM + exp-sum epilogue (no sim materialization) --------
// sim = A (bf16 [4096x1024]) @ P^T; per-element logit = sim * rt(col-mapped);
// per-row sum of exp(logit) accumulated via atomics; diag logit recorded.
// Bounded logits (|l| <= ~10.1) make the max-pass unnecessary.
__global__ __launch_bounds__(256) void gemm_ce_fused(const unsigned short* __restrict__ A,
                                                     const unsigned short* __restrict__ P,
                                                     const float* __restrict__ rt,
                                                     float* __restrict__ rowacc,
                                                     float* __restrict__ diag) {
  __shared__ __align__(16) unsigned short lA[128 * 32];
  __shared__ __align__(16) unsigned short lB[128 * 32];
  __shared__ float rowsum[2][128];
  const int tid = threadIdx.x;
  const int lane = tid & 63;
  const int wave = tid >> 6;
  const int m0 = blockIdx.y * 128;
  const int n0 = blockIdx.x * 128;
  const int s = blockIdx.z;
  const unsigned short* Bm = P + (size_t)s * BB * DD;
  const float* rt_s = rt + (size_t)s * RTS;

  f32x4 acc[4][4];
#pragma unroll
  for (int mi = 0; mi < 4; ++mi)
#pragma unroll
    for (int ni = 0; ni < 4; ++ni) acc[mi][ni] = (f32x4){0.f, 0.f, 0.f, 0.f};

  const int srow = lane >> 2;        // 0..15 within chunk
  const int scol = (lane & 3) * 8;   // bf16 element offset within row

  const int wm = (wave >> 1) * 64;
  const int wn = (wave & 1) * 64;
  const int fr = lane & 15;
  const int fk = (lane >> 4) * 8;

  for (int k0 = 0; k0 < DD; k0 += 32) {
#pragma unroll
    for (int c = 0; c < 2; ++c) {
      const int chunk = wave * 2 + c;            // 0..7, wave-uniform
      const int r = chunk * 16 + srow;           // 0..127
      const unsigned short* ga = A + (size_t)(m0 + r) * DD + k0 + scol;
      const unsigned short* gb = Bm + (size_t)(n0 + r) * DD + k0 + scol;
      async16(ga, &lA[chunk * 512]);
      async16(gb, &lB[chunk * 512]);
    }
    __syncthreads();

    bf16x8 af[4], bfr[4];
#pragma unroll
    for (int mi = 0; mi < 4; ++mi)
      af[mi] = *(const bf16x8*)&lA[(wm + mi * 16 + fr) * 32 + fk];
#pragma unroll
    for (int ni = 0; ni < 4; ++ni)
      bfr[ni] = *(const bf16x8*)&lB[(wn + ni * 16 + fr) * 32 + fk];
#pragma unroll
    for (int mi = 0; mi < 4; ++mi)
#pragma unroll
      for (int ni = 0; ni < 4; ++ni)
        acc[mi][ni] = __builtin_amdgcn_mfma_f32_16x16x32_bf16(af[mi], bfr[ni], acc[mi][ni], 0, 0, 0);
    __syncthreads();
  }

  // ---- fused epilogue ----
  // C layout per 16x16 tile: row=(lane>>4)*4+r, col=lane&15
  const int cm = (lane >> 4) * 4;
  const float rt0 = rt_s[0];
  float rtc[4], rtp[4];
#pragma unroll
  for (int ni = 0; ni < 4; ++ni) {
    const int col = n0 + wn + ni * 16 + fr;
    rtc[ni] = rt_s[col];
    rtp[ni] = rt_s[col + 1];   // padded stride makes col+1 safe
  }
#pragma unroll
  for (int mi = 0; mi < 4; ++mi) {
#pragma unroll
    for (int r = 0; r < 4; ++r) {
      const int rowi = m0 + wm + mi * 16 + cm + r;
      float esum = 0.f;
#pragma unroll
      for (int ni = 0; ni < 4; ++ni) {
        const int col = n0 + wn + ni * 16 + fr;
        const float v = acc[mi][ni][r];
        // col==rowi -> rt0 (pos, concat col 0); col<rowi -> rt[col+1]; col>rowi -> rt[col]
        const float rr = (col == rowi) ? rt0 : ((col < rowi) ? rtp[ni] : rtc[ni]);
        const float l = v * rr;
        if (col == rowi) diag[(size_t)s * BB + rowi] = l;
        esum += __expf(l);
      }
      // reduce across the 16 lanes of the quad (these hold the 16 cols)
#pragma unroll
      for (int off = 1; off < 16; off <<= 1) esum += __shfl_xor(esum, off, 64);
      if (fr == 0) rowsum[wave & 1][wm + mi * 16 + cm + r] = esum;
    }
  }
  __syncthreads();
  for (int t = tid; t < 128; t += 256)
    atomicAdd(&rowacc[(size_t)s * BB + m0 + t], rowsum[0][t] + rowsum[1][t]);
}

// ---------------- Phase 4: loss = sum_s w_s * (log(sumexp_s) - diag_s) ----------------
__global__ __launch_bounds__(256) void finish(const float* __restrict__ rowacc,
                                              const float* __restrict__ diag,
                                              float* __restrict__ out) {
  const int i = blockIdx.x * 256 + threadIdx.x;
  const float ce0 = logf(rowacc[i]) - diag[i];
  const float ce1 = logf(rowacc[BB + i]) - diag[BB + i];
  const float ce2 = logf(rowacc[2 * BB + i]) - diag[2 * BB + i];
  out[i] = ce0 * (1.0f / 27.0f) + ce1 * (1.0f / 9.0f) + ce2 * (1.0f / 3.0f);
}

extern "C" void kernel_launch(void* const* d_in, const int* in_sizes, int n_in,
                              void* d_out, int out_size, void* d_ws, size_t ws_size,
                              hipStream_t stream) {
  const float* anchor = (const float*)d_in[0];
  const int* index    = (const int*)d_in[1];
  const int* i2c0     = (const int*)d_in[2];
  const float* c0     = (const float*)d_in[3];
  const float* de0    = (const float*)d_in[4];
  const int* i2c1     = (const int*)d_in[5];
  const float* c1     = (const float*)d_in[6];
  const float* de1    = (const float*)d_in[7];
  const int* i2c2     = (const int*)d_in[8];
  const float* c2     = (const float*)d_in[9];
  const float* de2    = (const float*)d_in[10];

  char* ws = (char*)d_ws;
  const size_t A16_OFF = 0;                                      // 8 MB
  const size_t P16_OFF = A16_OFF + (size_t)BB * DD * 2;          // 24 MB (3 scales)
  const size_t RT_OFF  = P16_OFF + (size_t)3 * BB * DD * 2;      // 3*RTS floats
  const size_t ACC_OFF = RT_OFF + (size_t)3 * RTS * 4;           // 48 KB
  const size_t DIA_OFF = ACC_OFF + (size_t)3 * BB * 4;           // 48 KB

  unsigned short* a16 = (unsigned short*)(ws + A16_OFF);
  unsigned short* p16 = (unsigned short*)(ws + P16_OFF);
  float* rt     = (float*)(ws + RT_OFF);
  float* rowacc = (float*)(ws + ACC_OFF);
  float* diag   = (float*)(ws + DIA_OFF);
  float* out = (float*)d_out;

  norm_anchor<<<BB, 256, 0, stream>>>(anchor, a16);
  gather_norm<<<dim3(BB, 3), 256, 0, stream>>>(index, i2c0, i2c1, i2c2,
                                               c0, c1, c2, de0, de1, de2, p16, rt, rowacc);
  gemm_ce_fused<<<dim3(BB / 128, BB / 128, 3), 256, 0, stream>>>(a16, p16, rt, rowacc, diag);
  finish<<<BB / 256, 256, 0, stream>>>(rowacc, diag, out);
}